// Round 1
// baseline (1325.209 us; speedup 1.0000x reference)
//
#include <hip/hip_runtime.h>
#include <hip/hip_bf16.h>
#include <stdint.h>

typedef unsigned short u16;
typedef uint32_t u32;
typedef short s16x8 __attribute__((ext_vector_type(8)));
typedef float f32x4 __attribute__((ext_vector_type(4)));

#define SDIM 2048
#define EDIM 1024
#define MROWS 4096

static __device__ __forceinline__ float b2f(u16 v) {
    union { float f; u32 u; } c; c.u = ((u32)v) << 16; return c.f;
}
static __device__ __forceinline__ u16 f2b(float f) {
    union { float f; u32 u; } c; c.f = f;
    u32 u = c.u;
    u32 r = (u + 0x7FFFu + ((u >> 16) & 1u)) >> 16;
    return (u16)r;
}

// ---- dtype sniffer: bf16 buffer => even 16-bit words are bf16 values (exp field
// concentrated); fp32 buffer => even words are low mantissa bits (uniform). ----
__global__ void k_detect(const u16* __restrict__ x, int* __restrict__ flag) {
    __shared__ int cnt;
    if (threadIdx.x == 0) cnt = 0;
    __syncthreads();
    u16 v = x[threadIdx.x * 2];
    int e = (v >> 7) & 0xFF;
    int ok = (e >= 90 && e <= 144) ? 1 : 0;
    atomicAdd(&cnt, ok);
    __syncthreads();
    if (threadIdx.x == 0) flag[0] = (cnt >= 192) ? 1 : 0;
}

__global__ void k_convert(const void* __restrict__ src, u16* __restrict__ dst,
                          const int* __restrict__ flag, int n) {
    int i = blockIdx.x * blockDim.x + threadIdx.x;
    if (i >= n) return;
    if (flag[0]) dst[i] = ((const u16*)src)[i];
    else         dst[i] = f2b(((const float*)src)[i]);
}

// src: [K][N] row-major, dst: [N][K] row-major (coalesced writes)
__global__ void k_convert_t(const void* __restrict__ src, u16* __restrict__ dst,
                            const int* __restrict__ flag, int K, int N) {
    int i = blockIdx.x * blockDim.x + threadIdx.x;
    if (i >= K * N) return;
    int n = i / K;
    int k = i - n * K;
    long si = (long)k * N + n;
    if (flag[0]) dst[i] = ((const u16*)src)[si];
    else         dst[i] = f2b(((const float*)src)[si]);
}

// ---- bf16 MFMA GEMM: C[M,N] = A[M,K] @ Bt[N,K]^T + bias. 128x128 tile, 4 waves.
#define LDSP 40
__global__ __launch_bounds__(256) void k_gemm(
    const u16* __restrict__ A, const u16* __restrict__ Bt, const u16* __restrict__ bias,
    u16* __restrict__ Cb, float* __restrict__ Cf, const int* __restrict__ flag,
    int M, int N, int K, int is_final) {
    __shared__ u16 As[128 * LDSP];
    __shared__ u16 Bs[128 * LDSP];
    int t = threadIdx.x;
    int m0 = blockIdx.y * 128, n0 = blockIdx.x * 128;
    int wave = t >> 6, lane = t & 63;
    int wm = (wave >> 1) * 64, wn = (wave & 1) * 64;
    int lm = lane & 15, lk = (lane >> 4) * 8;

    f32x4 acc[4][4];
    f32x4 z = {0.f, 0.f, 0.f, 0.f};
    for (int mi = 0; mi < 4; ++mi)
        for (int ni = 0; ni < 4; ++ni) acc[mi][ni] = z;

    int e0 = t * 8;          int r0 = e0 >> 5, c0 = e0 & 31;
    int e1 = (256 + t) * 8;  int r1 = e1 >> 5, c1 = e1 & 31;

    for (int k0 = 0; k0 < K; k0 += 32) {
        uint4 av0 = *(const uint4*)(A  + (size_t)(m0 + r0) * K + k0 + c0);
        uint4 av1 = *(const uint4*)(A  + (size_t)(m0 + r1) * K + k0 + c1);
        uint4 bv0 = *(const uint4*)(Bt + (size_t)(n0 + r0) * K + k0 + c0);
        uint4 bv1 = *(const uint4*)(Bt + (size_t)(n0 + r1) * K + k0 + c1);
        *(uint4*)&As[r0 * LDSP + c0] = av0;
        *(uint4*)&As[r1 * LDSP + c1] = av1;
        *(uint4*)&Bs[r0 * LDSP + c0] = bv0;
        *(uint4*)&Bs[r1 * LDSP + c1] = bv1;
        __syncthreads();
        s16x8 af[4], bfr[4];
        for (int mi = 0; mi < 4; ++mi)
            af[mi] = *(const s16x8*)&As[(wm + mi * 16 + lm) * LDSP + lk];
        for (int ni = 0; ni < 4; ++ni)
            bfr[ni] = *(const s16x8*)&Bs[(wn + ni * 16 + lm) * LDSP + lk];
        for (int mi = 0; mi < 4; ++mi)
            for (int ni = 0; ni < 4; ++ni)
                acc[mi][ni] = __builtin_amdgcn_mfma_f32_16x16x32_bf16(
                    af[mi], bfr[ni], acc[mi][ni], 0, 0, 0);
        __syncthreads();
    }

    int store_f32 = is_final && (flag[0] == 0);
    int cn = lane & 15, cr = (lane >> 4) * 4;
    for (int ni = 0; ni < 4; ++ni) {
        int gn = n0 + wn + ni * 16 + cn;
        float bb = b2f(bias[gn]);
        for (int mi = 0; mi < 4; ++mi) {
            for (int r = 0; r < 4; ++r) {
                int gm = m0 + wm + mi * 16 + cr + r;
                float v = acc[mi][ni][r] + bb;
                size_t o = (size_t)gm * N + gn;
                if (store_f32) Cf[o] = v;
                else           Cb[o] = f2b(v);
            }
        }
    }
}

// ---- sparse attention: one wave per (row, head, batch). Allowed keys:
// strided = {j*128+120..127 : j < r/128}  plus  local = {(r/128)*128 .. r}.
__global__ __launch_bounds__(64) void k_attn(const u16* __restrict__ QKV,
                                             u16* __restrict__ AO) {
    int r = blockIdx.x, h = blockIdx.y, b = blockIdx.z;
    int lane = threadIdx.x;
    int qb = r >> 7;
    int nstr = qb << 3;
    int nk = nstr + (r & 127) + 1;   // <= 248
    __shared__ float p[256];
    __shared__ float qs[64];
    const u16* base = QKV + (size_t)b * SDIM * 3072;
    qs[lane] = b2f(base[(size_t)r * 3072 + h * 64 + lane]);
    __syncthreads();
    for (int i = lane; i < nk; i += 64) {
        int key = (i < nstr) ? (((i >> 3) << 7) + 120 + (i & 7))
                             : ((qb << 7) + (i - nstr));
        const u16* kp = base + (size_t)key * 3072 + 1024 + h * 64;
        float s = 0.f;
        for (int d = 0; d < 64; ++d) s += qs[d] * b2f(kp[d]);
        p[i] = s * 0.125f;
    }
    __syncthreads();
    float m = -1e30f;
    for (int i = lane; i < nk; i += 64) m = fmaxf(m, p[i]);
    for (int off = 32; off > 0; off >>= 1) m = fmaxf(m, __shfl_xor(m, off, 64));
    float sum = 0.f;
    for (int i = lane; i < nk; i += 64) {
        float e = __expf(p[i] - m);
        p[i] = e;
        sum += e;
    }
    for (int off = 32; off > 0; off >>= 1) sum += __shfl_xor(sum, off, 64);
    float inv = 1.f / sum;
    __syncthreads();
    float acc = 0.f;
    for (int i = 0; i < nk; ++i) {
        int key = (i < nstr) ? (((i >> 3) << 7) + 120 + (i & 7))
                             : ((qb << 7) + (i - nstr));
        acc += p[i] * b2f(base[(size_t)key * 3072 + 2048 + h * 64 + lane]);
    }
    AO[((size_t)(b * SDIM) + r) * EDIM + h * 64 + lane] = f2b(acc * inv);
}

extern "C" void kernel_launch(void* const* d_in, const int* in_sizes, int n_in,
                              void* d_out, int out_size, void* d_ws, size_t ws_size,
                              hipStream_t stream) {
    const void* X  = d_in[0];   // hidden_states [2,2048,1024]
    const void* Wa = d_in[1];   // W_attn [1024,3072]
    const void* ba = d_in[2];   // b_attn [3072]
    const void* Wp = d_in[3];   // W_proj [1024,1024]
    const void* bp = d_in[4];   // b_proj [1024]

    char* w = (char*)d_ws;
    int* flag = (int*)w;                        // 256 B
    u16* Xb   = (u16*)(w + 256);                // 4096*1024*2  = 8388608
    u16* WtA  = (u16*)(w + 8388864);            // 3072*1024*2  = 6291456
    u16* bA   = (u16*)(w + 14680320);           // 3072*2 (pad 8192)
    u16* WtP  = (u16*)(w + 14688512);           // 1024*1024*2  = 2097152
    u16* bP   = (u16*)(w + 16785664);           // 1024*2 (pad 4096)
    u16* QKV  = (u16*)(w + 16789760);           // 4096*3072*2  = 25165824
    u16* AO   = (u16*)(w + 41955584);           // 4096*1024*2  = 8388608
                                                // total ~50.3 MB

    k_detect<<<1, 256, 0, stream>>>((const u16*)X, flag);
    k_convert  <<<(4194304 + 255) / 256, 256, 0, stream>>>(X,  Xb,  flag, 4194304);
    k_convert_t<<<(3145728 + 255) / 256, 256, 0, stream>>>(Wa, WtA, flag, 1024, 3072);
    k_convert  <<<12, 256, 0, stream>>>(ba, bA, flag, 3072);
    k_convert_t<<<(1048576 + 255) / 256, 256, 0, stream>>>(Wp, WtP, flag, 1024, 1024);
    k_convert  <<<4, 256, 0, stream>>>(bp, bP, flag, 1024);

    k_gemm<<<dim3(24, 32), 256, 0, stream>>>(Xb, WtA, bA, QKV, nullptr, flag,
                                             4096, 3072, 1024, 0);
    k_attn<<<dim3(2048, 16, 2), 64, 0, stream>>>(QKV, AO);
    k_gemm<<<dim3(8, 32), 256, 0, stream>>>(AO, WtP, bP, (u16*)d_out, (float*)d_out,
                                            flag, 4096, 1024, 1024, 1);
}

// Round 2
// 205.236 us; speedup vs baseline: 6.4570x; 6.4570x over previous
//
#include <hip/hip_runtime.h>
#include <hip/hip_bf16.h>
#include <stdint.h>

typedef unsigned short u16;
typedef uint32_t u32;
typedef short s16x8 __attribute__((ext_vector_type(8)));
typedef float f32x4 __attribute__((ext_vector_type(4)));

#define SDIM 2048
#define EDIM 1024

static __device__ __forceinline__ float b2f(u16 v) {
    union { float f; u32 u; } c; c.u = ((u32)v) << 16; return c.f;
}
static __device__ __forceinline__ u16 f2b(float f) {
    union { float f; u32 u; } c; c.f = f;
    u32 u = c.u;
    u32 r = (u + 0x7FFFu + ((u >> 16) & 1u)) >> 16;
    return (u16)r;
}

// ---- dtype sniffer (unchanged, verified R1) ----
__global__ void k_detect(const u16* __restrict__ x, int* __restrict__ flag) {
    __shared__ int cnt;
    if (threadIdx.x == 0) cnt = 0;
    __syncthreads();
    u16 v = x[threadIdx.x * 2];
    int e = (v >> 7) & 0xFF;
    int ok = (e >= 90 && e <= 144) ? 1 : 0;
    atomicAdd(&cnt, ok);
    __syncthreads();
    if (threadIdx.x == 0) flag[0] = (cnt >= 192) ? 1 : 0;
}

__global__ void k_convert(const void* __restrict__ src, u16* __restrict__ dst,
                          const int* __restrict__ flag, int n) {
    int i = blockIdx.x * blockDim.x + threadIdx.x;
    if (i >= n) return;
    if (flag[0]) dst[i] = ((const u16*)src)[i];
    else         dst[i] = f2b(((const float*)src)[i]);
}

__global__ void k_convert_t(const void* __restrict__ src, u16* __restrict__ dst,
                            const int* __restrict__ flag, int K, int N) {
    int i = blockIdx.x * blockDim.x + threadIdx.x;
    if (i >= K * N) return;
    int n = i / K;
    int k = i - n * K;
    long si = (long)k * N + n;
    if (flag[0]) dst[i] = ((const u16*)src)[si];
    else         dst[i] = f2b(((const float*)src)[si]);
}

// ---- bf16 MFMA GEMM (unchanged, verified R1) ----
#define LDSP 40
__global__ __launch_bounds__(256) void k_gemm(
    const u16* __restrict__ A, const u16* __restrict__ Bt, const u16* __restrict__ bias,
    u16* __restrict__ Cb, float* __restrict__ Cf, const int* __restrict__ flag,
    int M, int N, int K, int is_final) {
    __shared__ u16 As[128 * LDSP];
    __shared__ u16 Bs[128 * LDSP];
    int t = threadIdx.x;
    int m0 = blockIdx.y * 128, n0 = blockIdx.x * 128;
    int wave = t >> 6, lane = t & 63;
    int wm = (wave >> 1) * 64, wn = (wave & 1) * 64;
    int lm = lane & 15, lk = (lane >> 4) * 8;

    f32x4 acc[4][4];
    f32x4 z = {0.f, 0.f, 0.f, 0.f};
    for (int mi = 0; mi < 4; ++mi)
        for (int ni = 0; ni < 4; ++ni) acc[mi][ni] = z;

    int e0 = t * 8;          int r0 = e0 >> 5, c0 = e0 & 31;
    int e1 = (256 + t) * 8;  int r1 = e1 >> 5, c1 = e1 & 31;

    for (int k0 = 0; k0 < K; k0 += 32) {
        uint4 av0 = *(const uint4*)(A  + (size_t)(m0 + r0) * K + k0 + c0);
        uint4 av1 = *(const uint4*)(A  + (size_t)(m0 + r1) * K + k0 + c1);
        uint4 bv0 = *(const uint4*)(Bt + (size_t)(n0 + r0) * K + k0 + c0);
        uint4 bv1 = *(const uint4*)(Bt + (size_t)(n0 + r1) * K + k0 + c1);
        *(uint4*)&As[r0 * LDSP + c0] = av0;
        *(uint4*)&As[r1 * LDSP + c1] = av1;
        *(uint4*)&Bs[r0 * LDSP + c0] = bv0;
        *(uint4*)&Bs[r1 * LDSP + c1] = bv1;
        __syncthreads();
        s16x8 af[4], bfr[4];
        for (int mi = 0; mi < 4; ++mi)
            af[mi] = *(const s16x8*)&As[(wm + mi * 16 + lm) * LDSP + lk];
        for (int ni = 0; ni < 4; ++ni)
            bfr[ni] = *(const s16x8*)&Bs[(wn + ni * 16 + lm) * LDSP + lk];
        for (int mi = 0; mi < 4; ++mi)
            for (int ni = 0; ni < 4; ++ni)
                acc[mi][ni] = __builtin_amdgcn_mfma_f32_16x16x32_bf16(
                    af[mi], bfr[ni], acc[mi][ni], 0, 0, 0);
        __syncthreads();
    }

    int store_f32 = is_final && (flag[0] == 0);
    int cn = lane & 15, cr = (lane >> 4) * 4;
    for (int ni = 0; ni < 4; ++ni) {
        int gn = n0 + wn + ni * 16 + cn;
        float bb = b2f(bias[gn]);
        for (int mi = 0; mi < 4; ++mi) {
            for (int r = 0; r < 4; ++r) {
                int gm = m0 + wm + mi * 16 + cr + r;
                float v = acc[mi][ni][r] + bb;
                size_t o = (size_t)gm * N + gn;
                if (store_f32) Cf[o] = v;
                else           Cb[o] = f2b(v);
            }
        }
    }
}

// ---- MFMA sparse attention ----
// Block = (qb, sb, h, b): 64 query rows (r0 = qb*128 + sb*64), 256 threads (4 waves,
// 16 rows each). Key set: nstr = 8*qb strided keys (last 8 of each earlier stride
// block) + local keys 0..sb*64+63 of block qb; padded to 256 with zeros/masks.
// S = Q K^T (mfma 16x16x32), in-register masked softmax, P->LDS (bf16), O = P V.
#define VP 264   // Vts row stride (elems): 528B, 16B-aligned, 2-way bank alias only
#define PP 264   // Ps  row stride
__global__ __launch_bounds__(256) void k_attn2(const u16* __restrict__ QKV,
                                               u16* __restrict__ AO) {
    int bx = blockIdx.x, h = blockIdx.y, b = blockIdx.z;
    int qb = bx >> 1, sb = bx & 1;
    int t = threadIdx.x, lane = t & 63, wave = t >> 6;
    int lm = lane & 15, q4 = lane >> 4;
    int nstr = qb << 3;
    int nloc = (sb << 6) + 64;
    int nk = nstr + nloc;               // <= 248
    int r0 = (qb << 7) + (sb << 6);

    __shared__ char smem[79872];
    u16* Vts = (u16*)smem;                       // 64 x 264 elems = 33792 B
    u16* Qs  = (u16*)(smem + 33792);             // 64 x 72  =  9216 B
    u16* Ks  = (u16*)(smem + 33792 + 9216);      // 256 x 72 = 36864 B
    u16* Ps  = (u16*)(smem + 33792);             // 64 x 264 (aliases Qs+Ks)

    const u16* base = QKV + (size_t)b * SDIM * 3072;

    // stage Q: 64 rows x 64 d = 512 x 8-elem chunks
    for (int c = t; c < 512; c += 256) {
        int r = c >> 3, d0 = (c & 7) << 3;
        *(uint4*)&Qs[r * 72 + d0] =
            *(const uint4*)(base + (size_t)(r0 + r) * 3072 + h * 64 + d0);
    }
    // stage K (natural) and V (transposed) for 256 padded keys
    uint4 zz = {0u, 0u, 0u, 0u};
    for (int c = t; c < 2048; c += 256) {
        int i = c >> 3, d0 = (c & 7) << 3;
        uint4 kv = zz, vv = zz;
        if (i < nk) {
            int key = (i < nstr) ? (((i >> 3) << 7) + 120 + (i & 7))
                                 : ((qb << 7) + (i - nstr));
            const u16* p = base + (size_t)key * 3072 + 1024 + h * 64 + d0;
            kv = *(const uint4*)p;
            vv = *(const uint4*)(p + 1024);
        }
        *(uint4*)&Ks[i * 72 + d0] = kv;
        u16 tmp[8]; *(uint4*)tmp = vv;
        for (int j = 0; j < 8; ++j) Vts[(d0 + j) * VP + i] = tmp[j];
    }
    __syncthreads();

    // S = Q K^T : wave owns rows [wave*16, +16) x all 256 key cols
    f32x4 acc[16];
    f32x4 z4 = {0.f, 0.f, 0.f, 0.f};
    for (int ni = 0; ni < 16; ++ni) acc[ni] = z4;
    s16x8 af0 = *(const s16x8*)&Qs[(wave * 16 + lm) * 72 + q4 * 8];
    s16x8 af1 = *(const s16x8*)&Qs[(wave * 16 + lm) * 72 + 32 + q4 * 8];
    for (int ni = 0; ni < 16; ++ni) {
        s16x8 bf0 = *(const s16x8*)&Ks[(ni * 16 + lm) * 72 + q4 * 8];
        s16x8 bf1 = *(const s16x8*)&Ks[(ni * 16 + lm) * 72 + 32 + q4 * 8];
        acc[ni] = __builtin_amdgcn_mfma_f32_16x16x32_bf16(af0, bf0, acc[ni], 0, 0, 0);
        acc[ni] = __builtin_amdgcn_mfma_f32_16x16x32_bf16(af1, bf1, acc[ni], 0, 0, 0);
    }
    __syncthreads();   // all waves done reading Qs/Ks; Ps may overwrite after this

    // masked softmax, in-register. C layout: col = ni*16+lm, row(in-tile) = q4*4+reg
    float mx[4] = {-3e38f, -3e38f, -3e38f, -3e38f};
    for (int ni = 0; ni < 16; ++ni) {
        int i = ni * 16 + lm;
        for (int reg = 0; reg < 4; ++reg) {
            int rl = (sb << 6) + wave * 16 + q4 * 4 + reg;  // row within 128-block
            bool valid = (i < nstr) || ((i - nstr) <= rl);
            float v = valid ? acc[ni][reg] * 0.125f : -3e38f;
            acc[ni][reg] = v;
            mx[reg] = fmaxf(mx[reg], v);
        }
    }
    for (int reg = 0; reg < 4; ++reg)
        for (int off = 1; off < 16; off <<= 1)
            mx[reg] = fmaxf(mx[reg], __shfl_xor(mx[reg], off, 64));
    float sm[4] = {0.f, 0.f, 0.f, 0.f};
    for (int ni = 0; ni < 16; ++ni)
        for (int reg = 0; reg < 4; ++reg) {
            float e = __expf(acc[ni][reg] - mx[reg]);
            acc[ni][reg] = e;
            sm[reg] += e;
        }
    for (int reg = 0; reg < 4; ++reg)
        for (int off = 1; off < 16; off <<= 1)
            sm[reg] += __shfl_xor(sm[reg], off, 64);
    float inv[4];
    for (int reg = 0; reg < 4; ++reg) inv[reg] = 1.f / sm[reg];

    // P -> LDS (bf16, A-operand-readable layout)
    for (int ni = 0; ni < 16; ++ni) {
        int i = ni * 16 + lm;
        for (int reg = 0; reg < 4; ++reg)
            Ps[(wave * 16 + q4 * 4 + reg) * PP + i] = f2b(acc[ni][reg]);
    }
    __syncthreads();

    // O = P V : rows [wave*16,+16) x 64 d cols, K=256
    f32x4 acc2[4];
    for (int ni2 = 0; ni2 < 4; ++ni2) acc2[ni2] = z4;
    for (int k0 = 0; k0 < 256; k0 += 32) {
        s16x8 pf = *(const s16x8*)&Ps[(wave * 16 + lm) * PP + k0 + q4 * 8];
        for (int ni2 = 0; ni2 < 4; ++ni2) {
            s16x8 vf = *(const s16x8*)&Vts[(ni2 * 16 + lm) * VP + k0 + q4 * 8];
            acc2[ni2] = __builtin_amdgcn_mfma_f32_16x16x32_bf16(pf, vf, acc2[ni2], 0, 0, 0);
        }
    }
    int srow = r0 + wave * 16 + q4 * 4;
    for (int ni2 = 0; ni2 < 4; ++ni2)
        for (int reg = 0; reg < 4; ++reg) {
            size_t o = ((size_t)(b * SDIM + srow + reg)) * EDIM + h * 64 + ni2 * 16 + lm;
            AO[o] = f2b(acc2[ni2][reg] * inv[reg]);
        }
}

extern "C" void kernel_launch(void* const* d_in, const int* in_sizes, int n_in,
                              void* d_out, int out_size, void* d_ws, size_t ws_size,
                              hipStream_t stream) {
    const void* X  = d_in[0];
    const void* Wa = d_in[1];
    const void* ba = d_in[2];
    const void* Wp = d_in[3];
    const void* bp = d_in[4];

    char* w = (char*)d_ws;
    int* flag = (int*)w;
    u16* Xb   = (u16*)(w + 256);
    u16* WtA  = (u16*)(w + 8388864);
    u16* bA   = (u16*)(w + 14680320);
    u16* WtP  = (u16*)(w + 14688512);
    u16* bP   = (u16*)(w + 16785664);
    u16* QKV  = (u16*)(w + 16789760);
    u16* AO   = (u16*)(w + 41955584);

    k_detect<<<1, 256, 0, stream>>>((const u16*)X, flag);
    k_convert  <<<(4194304 + 255) / 256, 256, 0, stream>>>(X,  Xb,  flag, 4194304);
    k_convert_t<<<(3145728 + 255) / 256, 256, 0, stream>>>(Wa, WtA, flag, 1024, 3072);
    k_convert  <<<12, 256, 0, stream>>>(ba, bA, flag, 3072);
    k_convert_t<<<(1048576 + 255) / 256, 256, 0, stream>>>(Wp, WtP, flag, 1024, 1024);
    k_convert  <<<4, 256, 0, stream>>>(bp, bP, flag, 1024);

    k_gemm<<<dim3(24, 32), 256, 0, stream>>>(Xb, WtA, bA, QKV, nullptr, flag,
                                             4096, 3072, 1024, 0);
    k_attn2<<<dim3(32, 16, 2), 256, 0, stream>>>(QKV, AO);
    k_gemm<<<dim3(8, 32), 256, 0, stream>>>(AO, WtP, bP, (u16*)d_out, (float*)d_out,
                                            flag, 4096, 1024, 1024, 1);
}

// Round 3
// 193.052 us; speedup vs baseline: 6.8645x; 1.0631x over previous
//
#include <hip/hip_runtime.h>
#include <hip/hip_bf16.h>
#include <stdint.h>

typedef unsigned short u16;
typedef uint32_t u32;
typedef short s16x8 __attribute__((ext_vector_type(8)));
typedef float f32x4 __attribute__((ext_vector_type(4)));

#define SDIM 2048
#define EDIM 1024

static __device__ __forceinline__ float b2f(u16 v) {
    union { float f; u32 u; } c; c.u = ((u32)v) << 16; return c.f;
}
static __device__ __forceinline__ u16 f2b(float f) {
    union { float f; u32 u; } c; c.f = f;
    u32 u = c.u;
    u32 r = (u + 0x7FFFu + ((u >> 16) & 1u)) >> 16;
    return (u16)r;
}

// async global->LDS, 16B per lane; LDS dest = wave-uniform base + lane*16
static __device__ __forceinline__ void gll16(const u16* g, u16* l) {
    __builtin_amdgcn_global_load_lds(
        (const __attribute__((address_space(1))) void*)g,
        (__attribute__((address_space(3))) void*)l, 16, 0, 0);
}

// ---- dtype sniffer (verified R1) ----
__global__ void k_detect(const u16* __restrict__ x, int* __restrict__ flag) {
    __shared__ int cnt;
    if (threadIdx.x == 0) cnt = 0;
    __syncthreads();
    u16 v = x[threadIdx.x * 2];
    int e = (v >> 7) & 0xFF;
    int ok = (e >= 90 && e <= 144) ? 1 : 0;
    atomicAdd(&cnt, ok);
    __syncthreads();
    if (threadIdx.x == 0) flag[0] = (cnt >= 192) ? 1 : 0;
}

// fused convert: X (copy/cvt), W_attn^T, W_proj^T — one launch
__global__ void k_prep(const void* __restrict__ X, const void* __restrict__ Wa,
                       const void* __restrict__ Wp, u16* __restrict__ Xb,
                       u16* __restrict__ WtA, u16* __restrict__ WtP,
                       const int* __restrict__ flag) {
    long i = (long)blockIdx.x * 256 + threadIdx.x;
    int f = flag[0];
    if (i < 4194304) {
        Xb[i] = f ? ((const u16*)X)[i] : f2b(((const float*)X)[i]);
        return;
    }
    i -= 4194304;
    if (i < 3145728) {               // WtA[n*1024+k] = Wa[k*3072+n]
        int n = (int)(i >> 10), k = (int)(i & 1023);
        long si = (long)k * 3072 + n;
        WtA[i] = f ? ((const u16*)Wa)[si] : f2b(((const float*)Wa)[si]);
        return;
    }
    i -= 3145728;
    if (i < 1048576) {               // WtP[n*1024+k] = Wp[k*1024+n]
        int n = (int)(i >> 10), k = (int)(i & 1023);
        long si = ((long)k << 10) + n;
        WtP[i] = f ? ((const u16*)Wp)[si] : f2b(((const float*)Wp)[si]);
    }
}

// ---- bf16 MFMA GEMM, m97-style: global_load_lds(16B) into unpadded LDS ----
// C[M,N] = A[M,K] @ Bt[N,K]^T + bias. 128x128 tile, BK=32, 4 waves.
__global__ __launch_bounds__(256) void k_gemm(
    const u16* __restrict__ A, const u16* __restrict__ Bt, const void* __restrict__ bias,
    u16* __restrict__ Cb, float* __restrict__ Cf, const int* __restrict__ flag,
    int M, int N, int K, int is_final) {
    __shared__ u16 As[128 * 32];
    __shared__ u16 Bs[128 * 32];
    int t = threadIdx.x;
    int m0 = blockIdx.y * 128, n0 = blockIdx.x * 128;
    int wave = t >> 6, lane = t & 63;
    int wm = (wave >> 1) * 64, wn = (wave & 1) * 64;
    int lm = lane & 15, lk = (lane >> 4) * 8;

    // staging: thread t owns elements t*8 (rows t/4, col (t&3)*8) and +2048
    int sr = t >> 2, sc = (t & 3) << 3;
    const u16* Ap = A + (size_t)(m0 + sr) * K + sc;
    const u16* Bp = Bt + (size_t)(n0 + sr) * K + sc;
    u16* Asw = As + wave * 512;      // wave-uniform LDS bases
    u16* Bsw = Bs + wave * 512;

    f32x4 acc[4][4];
    f32x4 z = {0.f, 0.f, 0.f, 0.f};
    for (int mi = 0; mi < 4; ++mi)
        for (int ni = 0; ni < 4; ++ni) acc[mi][ni] = z;

    for (int k0 = 0; k0 < K; k0 += 32) {
        gll16(Ap + k0, Asw);
        gll16(Ap + (size_t)64 * K + k0, Asw + 2048);
        gll16(Bp + k0, Bsw);
        gll16(Bp + (size_t)64 * K + k0, Bsw + 2048);
        __syncthreads();             // compiler emits vmcnt(0) drain before barrier
        s16x8 af[4], bfr[4];
        for (int mi = 0; mi < 4; ++mi)
            af[mi] = *(const s16x8*)&As[(wm + mi * 16 + lm) * 32 + lk];
        for (int ni = 0; ni < 4; ++ni)
            bfr[ni] = *(const s16x8*)&Bs[(wn + ni * 16 + lm) * 32 + lk];
        for (int mi = 0; mi < 4; ++mi)
            for (int ni = 0; ni < 4; ++ni)
                acc[mi][ni] = __builtin_amdgcn_mfma_f32_16x16x32_bf16(
                    af[mi], bfr[ni], acc[mi][ni], 0, 0, 0);
        __syncthreads();
    }

    int f = flag[0];
    int store_f32 = is_final && (f == 0);
    int cn = lane & 15, cr = (lane >> 4) * 4;
    for (int ni = 0; ni < 4; ++ni) {
        int gn = n0 + wn + ni * 16 + cn;
        float bb = f ? b2f(((const u16*)bias)[gn]) : ((const float*)bias)[gn];
        for (int mi = 0; mi < 4; ++mi) {
            for (int r = 0; r < 4; ++r) {
                int gm = m0 + wm + mi * 16 + cr + r;
                float v = acc[mi][ni][r] + bb;
                size_t o = (size_t)gm * N + gn;
                if (store_f32) Cf[o] = v;
                else           Cb[o] = f2b(v);
            }
        }
    }
}

// ---- MFMA sparse attention (verified R2) ----
#define VP 264
#define PP 264
__global__ __launch_bounds__(256) void k_attn2(const u16* __restrict__ QKV,
                                               u16* __restrict__ AO) {
    int bx = blockIdx.x, h = blockIdx.y, b = blockIdx.z;
    int qb = bx >> 1, sb = bx & 1;
    int t = threadIdx.x, lane = t & 63, wave = t >> 6;
    int lm = lane & 15, q4 = lane >> 4;
    int nstr = qb << 3;
    int nloc = (sb << 6) + 64;
    int nk = nstr + nloc;               // <= 248
    int r0 = (qb << 7) + (sb << 6);

    __shared__ char smem[79872];
    u16* Vts = (u16*)smem;                       // 64 x 264 = 33792 B
    u16* Qs  = (u16*)(smem + 33792);             // 64 x 72  =  9216 B
    u16* Ks  = (u16*)(smem + 33792 + 9216);      // 256 x 72 = 36864 B
    u16* Ps  = (u16*)(smem + 33792);             // aliases Qs+Ks

    const u16* base = QKV + (size_t)b * SDIM * 3072;

    for (int c = t; c < 512; c += 256) {
        int r = c >> 3, d0 = (c & 7) << 3;
        *(uint4*)&Qs[r * 72 + d0] =
            *(const uint4*)(base + (size_t)(r0 + r) * 3072 + h * 64 + d0);
    }
    uint4 zz = {0u, 0u, 0u, 0u};
    for (int c = t; c < 2048; c += 256) {
        int i = c >> 3, d0 = (c & 7) << 3;
        uint4 kv = zz, vv = zz;
        if (i < nk) {
            int key = (i < nstr) ? (((i >> 3) << 7) + 120 + (i & 7))
                                 : ((qb << 7) + (i - nstr));
            const u16* p = base + (size_t)key * 3072 + 1024 + h * 64 + d0;
            kv = *(const uint4*)p;
            vv = *(const uint4*)(p + 1024);
        }
        *(uint4*)&Ks[i * 72 + d0] = kv;
        u16 tmp[8]; *(uint4*)tmp = vv;
        for (int j = 0; j < 8; ++j) Vts[(d0 + j) * VP + i] = tmp[j];
    }
    __syncthreads();

    f32x4 acc[16];
    f32x4 z4 = {0.f, 0.f, 0.f, 0.f};
    for (int ni = 0; ni < 16; ++ni) acc[ni] = z4;
    s16x8 af0 = *(const s16x8*)&Qs[(wave * 16 + lm) * 72 + q4 * 8];
    s16x8 af1 = *(const s16x8*)&Qs[(wave * 16 + lm) * 72 + 32 + q4 * 8];
    for (int ni = 0; ni < 16; ++ni) {
        s16x8 bf0 = *(const s16x8*)&Ks[(ni * 16 + lm) * 72 + q4 * 8];
        s16x8 bf1 = *(const s16x8*)&Ks[(ni * 16 + lm) * 72 + 32 + q4 * 8];
        acc[ni] = __builtin_amdgcn_mfma_f32_16x16x32_bf16(af0, bf0, acc[ni], 0, 0, 0);
        acc[ni] = __builtin_amdgcn_mfma_f32_16x16x32_bf16(af1, bf1, acc[ni], 0, 0, 0);
    }
    __syncthreads();

    float mx[4] = {-3e38f, -3e38f, -3e38f, -3e38f};
    for (int ni = 0; ni < 16; ++ni) {
        int i = ni * 16 + lm;
        for (int reg = 0; reg < 4; ++reg) {
            int rl = (sb << 6) + wave * 16 + q4 * 4 + reg;
            bool valid = (i < nstr) || ((i - nstr) <= rl);
            float v = valid ? acc[ni][reg] * 0.125f : -3e38f;
            acc[ni][reg] = v;
            mx[reg] = fmaxf(mx[reg], v);
        }
    }
    for (int reg = 0; reg < 4; ++reg)
        for (int off = 1; off < 16; off <<= 1)
            mx[reg] = fmaxf(mx[reg], __shfl_xor(mx[reg], off, 64));
    float sm[4] = {0.f, 0.f, 0.f, 0.f};
    for (int ni = 0; ni < 16; ++ni)
        for (int reg = 0; reg < 4; ++reg) {
            float e = __expf(acc[ni][reg] - mx[reg]);
            acc[ni][reg] = e;
            sm[reg] += e;
        }
    for (int reg = 0; reg < 4; ++reg)
        for (int off = 1; off < 16; off <<= 1)
            sm[reg] += __shfl_xor(sm[reg], off, 64);
    float inv[4];
    for (int reg = 0; reg < 4; ++reg) inv[reg] = 1.f / sm[reg];

    for (int ni = 0; ni < 16; ++ni) {
        int i = ni * 16 + lm;
        for (int reg = 0; reg < 4; ++reg)
            Ps[(wave * 16 + q4 * 4 + reg) * PP + i] = f2b(acc[ni][reg]);
    }
    __syncthreads();

    f32x4 acc2[4];
    for (int ni2 = 0; ni2 < 4; ++ni2) acc2[ni2] = z4;
    for (int k0 = 0; k0 < 256; k0 += 32) {
        s16x8 pf = *(const s16x8*)&Ps[(wave * 16 + lm) * PP + k0 + q4 * 8];
        for (int ni2 = 0; ni2 < 4; ++ni2) {
            s16x8 vf = *(const s16x8*)&Vts[(ni2 * 16 + lm) * VP + k0 + q4 * 8];
            acc2[ni2] = __builtin_amdgcn_mfma_f32_16x16x32_bf16(pf, vf, acc2[ni2], 0, 0, 0);
        }
    }
    int srow = r0 + wave * 16 + q4 * 4;
    for (int ni2 = 0; ni2 < 4; ++ni2)
        for (int reg = 0; reg < 4; ++reg) {
            size_t o = ((size_t)(b * SDIM + srow + reg)) * EDIM + h * 64 + ni2 * 16 + lm;
            AO[o] = f2b(acc2[ni2][reg] * inv[reg]);
        }
}

extern "C" void kernel_launch(void* const* d_in, const int* in_sizes, int n_in,
                              void* d_out, int out_size, void* d_ws, size_t ws_size,
                              hipStream_t stream) {
    const void* X  = d_in[0];
    const void* Wa = d_in[1];
    const void* ba = d_in[2];
    const void* Wp = d_in[3];
    const void* bp = d_in[4];

    char* w = (char*)d_ws;
    int* flag = (int*)w;
    u16* Xb   = (u16*)(w + 256);
    u16* WtA  = (u16*)(w + 8388864);
    u16* WtP  = (u16*)(w + 14688512);
    u16* QKV  = (u16*)(w + 16789760);
    u16* AO   = (u16*)(w + 41955584);

    k_detect<<<1, 256, 0, stream>>>((const u16*)X, flag);
    k_prep<<<32768, 256, 0, stream>>>(X, Wa, Wp, Xb, WtA, WtP, flag);

    k_gemm<<<dim3(24, 32), 256, 0, stream>>>(Xb, WtA, ba, QKV, nullptr, flag,
                                             4096, 3072, 1024, 0);
    k_attn2<<<dim3(32, 16, 2), 256, 0, stream>>>(QKV, AO);
    k_gemm<<<dim3(8, 32), 256, 0, stream>>>(AO, WtP, bp, (u16*)d_out, (float*)d_out,
                                            flag, 4096, 1024, 1024, 1);
}

// Round 4
// 176.504 us; speedup vs baseline: 7.5081x; 1.0937x over previous
//
#include <hip/hip_runtime.h>
#include <hip/hip_bf16.h>
#include <stdint.h>

typedef unsigned short u16;
typedef uint32_t u32;
typedef short s16x8 __attribute__((ext_vector_type(8)));
typedef float f32x4 __attribute__((ext_vector_type(4)));

#define SDIM 2048
#define EDIM 1024

static __device__ __forceinline__ float b2f(u16 v) {
    union { float f; u32 u; } c; c.u = ((u32)v) << 16; return c.f;
}
static __device__ __forceinline__ u16 f2b(float f) {
    union { float f; u32 u; } c; c.f = f;
    u32 u = c.u;
    u32 r = (u + 0x7FFFu + ((u >> 16) & 1u)) >> 16;
    return (u16)r;
}
static __device__ __forceinline__ void gll16(const u16* g, u16* l) {
    __builtin_amdgcn_global_load_lds(
        (const __attribute__((address_space(1))) void*)g,
        (__attribute__((address_space(3))) void*)l, 16, 0, 0);
}

// ---- dtype sniffer (verified R1) ----
__global__ void k_detect(const u16* __restrict__ x, int* __restrict__ flag) {
    __shared__ int cnt;
    if (threadIdx.x == 0) cnt = 0;
    __syncthreads();
    u16 v = x[threadIdx.x * 2];
    int e = (v >> 7) & 0xFF;
    int ok = (e >= 90 && e <= 144) ? 1 : 0;
    atomicAdd(&cnt, ok);
    __syncthreads();
    if (threadIdx.x == 0) flag[0] = (cnt >= 192) ? 1 : 0;
}

// ---- X convert (fp32 path only; bf16 path reads X directly in GEMM1) ----
__global__ void k_convx(const void* __restrict__ X, u16* __restrict__ Xb,
                        const int* __restrict__ flag) {
    if (flag[0]) return;
    long i = ((long)blockIdx.x * 256 + threadIdx.x) * 8;
    const float* s = (const float*)X;
    u16 o[8];
    for (int j = 0; j < 8; ++j) o[j] = f2b(s[i + j]);
    *(uint4*)&Xb[i] = *(uint4*)o;
}

// ---- LDS-tiled weight transpose+convert: dst[n][k] = cvt(src[k][n]) ----
// z=0: Wa [1024][3072] -> WtA [3072][1024];  z=1: Wp [1024][1024] -> WtP
__global__ __launch_bounds__(256) void k_trans(
    const void* __restrict__ Wa, const void* __restrict__ Wp,
    u16* __restrict__ WtA, u16* __restrict__ WtP, const int* __restrict__ flag) {
    int z = blockIdx.z;
    if (z == 1 && blockIdx.x >= 16) return;
    const void* src = z ? Wp : Wa;
    u16* dst = z ? WtP : WtA;
    int Nsrc = z ? 1024 : 3072;
    int n0 = blockIdx.x * 64, k0 = blockIdx.y * 64;
    int t = threadIdx.x, f = flag[0];
    __shared__ u16 L[64 * 72];
    int r = t >> 2, c0 = (t & 3) * 16;
    u16 val[16];
    if (f) {
        const u16* s = (const u16*)src + (size_t)(k0 + r) * Nsrc + n0 + c0;
        *(uint4*)&val[0] = *(const uint4*)s;
        *(uint4*)&val[8] = *(const uint4*)(s + 8);
    } else {
        const float* s = (const float*)src + (size_t)(k0 + r) * Nsrc + n0 + c0;
        for (int j = 0; j < 16; ++j) val[j] = f2b(s[j]);
    }
    for (int j = 0; j < 16; ++j) L[(c0 + j) * 72 + r] = val[j];
    __syncthreads();
    int kc0 = (t & 3) * 16;
    uint4 o0 = *(const uint4*)&L[r * 72 + kc0];
    uint4 o1 = *(const uint4*)&L[r * 72 + kc0 + 8];
    u16* d = dst + (size_t)(n0 + r) * 1024 + k0 + kc0;
    *(uint4*)d = o0;
    *(uint4*)(d + 8) = o1;
}

// ---- GEMM1: QKV = X @ WtA^T + b. M=4096 N=3072 K=1024, 128x128 tile, BK=64 ----
__global__ __launch_bounds__(256) void k_gemm1(
    const u16* __restrict__ Xraw, const u16* __restrict__ Xb,
    const u16* __restrict__ Bt, const void* __restrict__ bias,
    u16* __restrict__ C, const int* __restrict__ flag) {
    const int K = 1024, N = 3072;
    __shared__ u16 As[128 * 64];
    __shared__ u16 Bs[128 * 64];
    int f = flag[0];
    const u16* A = f ? Xraw : Xb;
    int t = threadIdx.x, wave = t >> 6, lane = t & 63;
    int m0 = blockIdx.y * 128, n0 = blockIdx.x * 128;
    int wm = (wave >> 1) * 64, wn = (wave & 1) * 64;
    int lm = lane & 15, lk = (lane >> 4) * 8;
    int sr = t >> 2, sc = (t & 3) * 8;
    const u16* Ap = A + (size_t)(m0 + sr) * K + sc;
    const u16* Bp = Bt + (size_t)(n0 + sr) * K + sc;
    u16* Asw = As + wave * 512;
    u16* Bsw = Bs + wave * 512;

    f32x4 acc[4][4];
    f32x4 z = {0.f, 0.f, 0.f, 0.f};
    for (int mi = 0; mi < 4; ++mi)
        for (int ni = 0; ni < 4; ++ni) acc[mi][ni] = z;

    for (int k0 = 0; k0 < K; k0 += 64) {
        // half0 (cols k0..k0+31) at LDS 0; half1 (k0+32..63) at LDS +4096
        gll16(Ap + k0, Asw);
        gll16(Ap + (size_t)64 * K + k0, Asw + 2048);
        gll16(Ap + k0 + 32, Asw + 4096);
        gll16(Ap + (size_t)64 * K + k0 + 32, Asw + 6144);
        gll16(Bp + k0, Bsw);
        gll16(Bp + (size_t)64 * K + k0, Bsw + 2048);
        gll16(Bp + k0 + 32, Bsw + 4096);
        gll16(Bp + (size_t)64 * K + k0 + 32, Bsw + 6144);
        __syncthreads();
        for (int kh = 0; kh < 2; ++kh) {
            const u16* Ab = As + kh * 4096;
            const u16* Bb = Bs + kh * 4096;
            s16x8 af[4], bfr[4];
            for (int mi = 0; mi < 4; ++mi)
                af[mi] = *(const s16x8*)&Ab[(wm + mi * 16 + lm) * 32 + lk];
            for (int ni = 0; ni < 4; ++ni)
                bfr[ni] = *(const s16x8*)&Bb[(wn + ni * 16 + lm) * 32 + lk];
            for (int mi = 0; mi < 4; ++mi)
                for (int ni = 0; ni < 4; ++ni)
                    acc[mi][ni] = __builtin_amdgcn_mfma_f32_16x16x32_bf16(
                        af[mi], bfr[ni], acc[mi][ni], 0, 0, 0);
        }
        __syncthreads();
    }

    int cn = lane & 15, cr = (lane >> 4) * 4;
    for (int ni = 0; ni < 4; ++ni) {
        int gn = n0 + wn + ni * 16 + cn;
        float bb = f ? b2f(((const u16*)bias)[gn]) : ((const float*)bias)[gn];
        for (int mi = 0; mi < 4; ++mi)
            for (int r = 0; r < 4; ++r) {
                int gm = m0 + wm + mi * 16 + cr + r;
                C[(size_t)gm * N + gn] = f2b(acc[mi][ni][r] + bb);
            }
    }
}

// ---- GEMM2: out = AO @ WtP^T + b. M=4096 N=1024 K=1024, 64x128 tile, BK=32 ----
__global__ __launch_bounds__(256) void k_gemm2(
    const u16* __restrict__ A, const u16* __restrict__ Bt, const void* __restrict__ bias,
    u16* __restrict__ Cb, float* __restrict__ Cf, const int* __restrict__ flag) {
    const int K = 1024, N = 1024;
    __shared__ u16 As[64 * 32];
    __shared__ u16 Bs[128 * 32];
    int t = threadIdx.x, wave = t >> 6, lane = t & 63;
    int m0 = blockIdx.y * 64, n0 = blockIdx.x * 128;
    int wm = (wave >> 1) * 32, wn = (wave & 1) * 64;
    int lm = lane & 15, lk = (lane >> 4) * 8;
    int sr = t >> 2, sc = (t & 3) * 8;
    const u16* Ap = A + (size_t)(m0 + sr) * K + sc;
    const u16* Bp = Bt + (size_t)(n0 + sr) * K + sc;
    u16* Asw = As + wave * 512;
    u16* Bsw = Bs + wave * 512;

    f32x4 acc[2][4];
    f32x4 z = {0.f, 0.f, 0.f, 0.f};
    for (int mi = 0; mi < 2; ++mi)
        for (int ni = 0; ni < 4; ++ni) acc[mi][ni] = z;

    for (int k0 = 0; k0 < K; k0 += 32) {
        gll16(Ap + k0, Asw);                       // A rows 0..63
        gll16(Bp + k0, Bsw);                       // B rows 0..63
        gll16(Bp + (size_t)64 * K + k0, Bsw + 2048); // B rows 64..127
        __syncthreads();
        s16x8 af[2], bfr[4];
        for (int mi = 0; mi < 2; ++mi)
            af[mi] = *(const s16x8*)&As[(wm + mi * 16 + lm) * 32 + lk];
        for (int ni = 0; ni < 4; ++ni)
            bfr[ni] = *(const s16x8*)&Bs[(wn + ni * 16 + lm) * 32 + lk];
        for (int mi = 0; mi < 2; ++mi)
            for (int ni = 0; ni < 4; ++ni)
                acc[mi][ni] = __builtin_amdgcn_mfma_f32_16x16x32_bf16(
                    af[mi], bfr[ni], acc[mi][ni], 0, 0, 0);
        __syncthreads();
    }

    int f = flag[0];
    int store_f32 = (f == 0);
    int cn = lane & 15, cr = (lane >> 4) * 4;
    for (int ni = 0; ni < 4; ++ni) {
        int gn = n0 + wn + ni * 16 + cn;
        float bb = f ? b2f(((const u16*)bias)[gn]) : ((const float*)bias)[gn];
        for (int mi = 0; mi < 2; ++mi)
            for (int r = 0; r < 4; ++r) {
                int gm = m0 + wm + mi * 16 + cr + r;
                float v = acc[mi][ni][r] + bb;
                size_t o = (size_t)gm * N + gn;
                if (store_f32) Cf[o] = v;
                else           Cb[o] = f2b(v);
            }
    }
}

// ---- MFMA sparse attention; V staged via register 8x8 transpose ----
#define VP 264
#define PP 264
__global__ __launch_bounds__(256) void k_attn3(const u16* __restrict__ QKV,
                                               u16* __restrict__ AO) {
    int bx = blockIdx.x, h = blockIdx.y, b = blockIdx.z;
    int qb = bx >> 1, sb = bx & 1;
    int t = threadIdx.x, lane = t & 63, wave = t >> 6;
    int lm = lane & 15, q4 = lane >> 4;
    int nstr = qb << 3;
    int nk = nstr + (sb << 6) + 64;     // <= 248
    int r0 = (qb << 7) + (sb << 6);

    __shared__ char smem[79872];
    u16* Vts = (u16*)smem;                       // 64 x 264 = 33792 B
    u16* Qs  = (u16*)(smem + 33792);             // 64 x 72
    u16* Ks  = (u16*)(smem + 33792 + 9216);      // 256 x 72
    u16* Ps  = (u16*)(smem + 33792);             // aliases Qs+Ks

    const u16* base = QKV + (size_t)b * SDIM * 3072;

    // Q: 64 rows x 64 d
    for (int c = t; c < 512; c += 256) {
        int r = c >> 3, d0 = (c & 7) << 3;
        *(uint4*)&Qs[r * 72 + d0] =
            *(const uint4*)(base + (size_t)(r0 + r) * 3072 + h * 64 + d0);
    }
    // K natural (garbage-pad tolerated by softmax mask — still zero for safety)
    uint4 zz = {0u, 0u, 0u, 0u};
    for (int c = t; c < 2048; c += 256) {
        int i = c >> 3, d0 = (c & 7) << 3;
        uint4 kv = zz;
        if (i < nk) {
            int key = (i < nstr) ? (((i >> 3) << 7) + 120 + (i & 7))
                                 : ((qb << 7) + (i - nstr));
            kv = *(const uint4*)(base + (size_t)key * 3072 + 1024 + h * 64 + d0);
        }
        *(uint4*)&Ks[i * 72 + d0] = kv;
    }
    // V transposed: thread owns keys i0..i0+7 x d0..d0+7; 8x8 register transpose
    {
        int i0 = (t & 31) * 8, d0 = (t >> 5) * 8;
        u16 m8[8][8];
        for (int r = 0; r < 8; ++r) {
            int i = i0 + r;
            uint4 vv = zz;
            if (i < nk) {
                int key = (i < nstr) ? (((i >> 3) << 7) + 120 + (i & 7))
                                     : ((qb << 7) + (i - nstr));
                vv = *(const uint4*)(base + (size_t)key * 3072 + 2048 + h * 64 + d0);
            }
            *(uint4*)m8[r] = vv;
        }
        for (int j = 0; j < 8; ++j) {
            u16 o[8];
            for (int r = 0; r < 8; ++r) o[r] = m8[r][j];
            *(uint4*)&Vts[(d0 + j) * VP + i0] = *(uint4*)o;
        }
    }
    __syncthreads();

    // S = Q K^T
    f32x4 acc[16];
    f32x4 z4 = {0.f, 0.f, 0.f, 0.f};
    for (int ni = 0; ni < 16; ++ni) acc[ni] = z4;
    s16x8 af0 = *(const s16x8*)&Qs[(wave * 16 + lm) * 72 + q4 * 8];
    s16x8 af1 = *(const s16x8*)&Qs[(wave * 16 + lm) * 72 + 32 + q4 * 8];
    for (int ni = 0; ni < 16; ++ni) {
        s16x8 bf0 = *(const s16x8*)&Ks[(ni * 16 + lm) * 72 + q4 * 8];
        s16x8 bf1 = *(const s16x8*)&Ks[(ni * 16 + lm) * 72 + 32 + q4 * 8];
        acc[ni] = __builtin_amdgcn_mfma_f32_16x16x32_bf16(af0, bf0, acc[ni], 0, 0, 0);
        acc[ni] = __builtin_amdgcn_mfma_f32_16x16x32_bf16(af1, bf1, acc[ni], 0, 0, 0);
    }
    __syncthreads();

    // masked softmax in C-layout registers
    float mx[4] = {-3e38f, -3e38f, -3e38f, -3e38f};
    for (int ni = 0; ni < 16; ++ni) {
        int i = ni * 16 + lm;
        for (int reg = 0; reg < 4; ++reg) {
            int rl = (sb << 6) + wave * 16 + q4 * 4 + reg;
            bool valid = (i < nstr) || ((i - nstr) <= rl);
            float v = valid ? acc[ni][reg] * 0.125f : -3e38f;
            acc[ni][reg] = v;
            mx[reg] = fmaxf(mx[reg], v);
        }
    }
    for (int reg = 0; reg < 4; ++reg)
        for (int off = 1; off < 16; off <<= 1)
            mx[reg] = fmaxf(mx[reg], __shfl_xor(mx[reg], off, 64));
    float sm[4] = {0.f, 0.f, 0.f, 0.f};
    for (int ni = 0; ni < 16; ++ni)
        for (int reg = 0; reg < 4; ++reg) {
            float e = __expf(acc[ni][reg] - mx[reg]);
            acc[ni][reg] = e;
            sm[reg] += e;
        }
    for (int reg = 0; reg < 4; ++reg)
        for (int off = 1; off < 16; off <<= 1)
            sm[reg] += __shfl_xor(sm[reg], off, 64);
    float inv[4];
    for (int reg = 0; reg < 4; ++reg) inv[reg] = 1.f / sm[reg];

    for (int ni = 0; ni < 16; ++ni) {
        int i = ni * 16 + lm;
        for (int reg = 0; reg < 4; ++reg)
            Ps[(wave * 16 + q4 * 4 + reg) * PP + i] = f2b(acc[ni][reg]);
    }
    __syncthreads();

    // O = P V
    f32x4 acc2[4];
    for (int ni2 = 0; ni2 < 4; ++ni2) acc2[ni2] = z4;
    for (int k0 = 0; k0 < 256; k0 += 32) {
        s16x8 pf = *(const s16x8*)&Ps[(wave * 16 + lm) * PP + k0 + q4 * 8];
        for (int ni2 = 0; ni2 < 4; ++ni2) {
            s16x8 vf = *(const s16x8*)&Vts[(ni2 * 16 + lm) * VP + k0 + q4 * 8];
            acc2[ni2] = __builtin_amdgcn_mfma_f32_16x16x32_bf16(pf, vf, acc2[ni2], 0, 0, 0);
        }
    }
    int srow = r0 + wave * 16 + q4 * 4;
    for (int ni2 = 0; ni2 < 4; ++ni2)
        for (int reg = 0; reg < 4; ++reg) {
            size_t o = ((size_t)(b * SDIM + srow + reg)) * EDIM + h * 64 + ni2 * 16 + lm;
            AO[o] = f2b(acc2[ni2][reg] * inv[reg]);
        }
}

extern "C" void kernel_launch(void* const* d_in, const int* in_sizes, int n_in,
                              void* d_out, int out_size, void* d_ws, size_t ws_size,
                              hipStream_t stream) {
    const void* X  = d_in[0];
    const void* Wa = d_in[1];
    const void* ba = d_in[2];
    const void* Wp = d_in[3];
    const void* bp = d_in[4];

    char* w = (char*)d_ws;
    int* flag = (int*)w;
    u16* Xb   = (u16*)(w + 256);
    u16* WtA  = (u16*)(w + 8388864);
    u16* WtP  = (u16*)(w + 14688512);
    u16* QKV  = (u16*)(w + 16789760);
    u16* AO   = (u16*)(w + 41955584);

    k_detect<<<1, 256, 0, stream>>>((const u16*)X, flag);
    k_convx<<<2048, 256, 0, stream>>>(X, Xb, flag);
    k_trans<<<dim3(48, 16, 2), 256, 0, stream>>>(Wa, Wp, WtA, WtP, flag);

    k_gemm1<<<dim3(24, 32), 256, 0, stream>>>((const u16*)X, Xb, WtA, ba, QKV, flag);
    k_attn3<<<dim3(32, 16, 2), 256, 0, stream>>>(QKV, AO);
    k_gemm2<<<dim3(8, 64), 256, 0, stream>>>(AO, WtP, bp, (u16*)d_out, (float*)d_out,
                                             flag);
}

// Round 5
// 169.578 us; speedup vs baseline: 7.8147x; 1.0408x over previous
//
#include <hip/hip_runtime.h>
#include <hip/hip_bf16.h>
#include <stdint.h>

typedef unsigned short u16;
typedef uint32_t u32;
typedef short s16x8 __attribute__((ext_vector_type(8)));
typedef float f32x4 __attribute__((ext_vector_type(4)));

#define SDIM 2048
#define EDIM 1024

static __device__ __forceinline__ float b2f(u16 v) {
    union { float f; u32 u; } c; c.u = ((u32)v) << 16; return c.f;
}
static __device__ __forceinline__ u16 f2b(float f) {
    union { float f; u32 u; } c; c.f = f;
    u32 u = c.u;
    u32 r = (u + 0x7FFFu + ((u >> 16) & 1u)) >> 16;
    return (u16)r;
}
static __device__ __forceinline__ void gll16(const u16* g, u16* l) {
    __builtin_amdgcn_global_load_lds(
        (const __attribute__((address_space(1))) void*)g,
        (__attribute__((address_space(3))) void*)l, 16, 0, 0);
}

// per-wave dtype sniff (replaces k_detect; same decision rule, verified R1):
// bf16 buffer -> even 16-bit words are bf16 values, exponent in [90,144] ~always;
// fp32 buffer -> even words are low mantissa bits, ~21% hit rate.
static __device__ __forceinline__ int sniff_bf16(const u16* __restrict__ x) {
    u16 v = x[(threadIdx.x & 63) * 2];
    int e = (v >> 7) & 0xFF;
    unsigned long long m = __ballot(e >= 90 && e <= 144);
    return __popcll(m) >= 48;
}

// ---- fused prep: z=0 Wa^T, z=1 Wp^T (LDS-tiled), z=2 X convert (fp32 path) ----
__global__ __launch_bounds__(256) void k_prep(
    const void* __restrict__ X, const void* __restrict__ Wa,
    const void* __restrict__ Wp, u16* __restrict__ Xb,
    u16* __restrict__ WtA, u16* __restrict__ WtP) {
    int f = sniff_bf16((const u16*)X);
    int z = blockIdx.z;
    int t = threadIdx.x;
    if (z == 2) {
        if (f) return;                       // bf16 path: gemm1 reads X directly
        const float* s = (const float*)X;
        int bid = blockIdx.y * 48 + blockIdx.x;     // 0..767
        for (int c = bid; c < 2048; c += 768) {
            long i = ((long)c * 256 + t) * 8;
            u16 o[8];
            for (int j = 0; j < 8; ++j) o[j] = f2b(s[i + j]);
            *(uint4*)&Xb[i] = *(uint4*)o;
        }
        return;
    }
    if (z == 1 && blockIdx.x >= 16) return;
    const void* src = z ? Wp : Wa;
    u16* dst = z ? WtP : WtA;
    int Nsrc = z ? 1024 : 3072;
    int n0 = blockIdx.x * 64, k0 = blockIdx.y * 64;
    __shared__ u16 L[64 * 72];
    int r = t >> 2, c0 = (t & 3) * 16;
    u16 val[16];
    if (f) {
        const u16* s = (const u16*)src + (size_t)(k0 + r) * Nsrc + n0 + c0;
        *(uint4*)&val[0] = *(const uint4*)s;
        *(uint4*)&val[8] = *(const uint4*)(s + 8);
    } else {
        const float* s = (const float*)src + (size_t)(k0 + r) * Nsrc + n0 + c0;
        for (int j = 0; j < 16; ++j) val[j] = f2b(s[j]);
    }
    for (int j = 0; j < 16; ++j) L[(c0 + j) * 72 + r] = val[j];
    __syncthreads();
    uint4 o0 = *(const uint4*)&L[r * 72 + c0];
    uint4 o1 = *(const uint4*)&L[r * 72 + c0 + 8];
    u16* d = dst + (size_t)(n0 + r) * 1024 + k0 + c0;
    *(uint4*)d = o0;
    *(uint4*)(d + 8) = o1;
}

// ---- GEMM1: QKV = X @ WtA^T + b. M=4096 N=3072 K=1024, 128x128, BK=64 ----
__global__ __launch_bounds__(256) void k_gemm1(
    const u16* __restrict__ Xraw, const u16* __restrict__ Xb,
    const u16* __restrict__ Bt, const void* __restrict__ bias,
    u16* __restrict__ C) {
    const int K = 1024, N = 3072;
    __shared__ u16 As[128 * 64];
    __shared__ u16 Bs[128 * 64];
    int f = sniff_bf16(Xraw);
    const u16* A = f ? Xraw : Xb;
    int t = threadIdx.x, wave = t >> 6, lane = t & 63;
    int m0 = blockIdx.y * 128, n0 = blockIdx.x * 128;
    int wm = (wave >> 1) * 64, wn = (wave & 1) * 64;
    int lm = lane & 15, lk = (lane >> 4) * 8;
    int sr = t >> 2, sc = (t & 3) * 8;
    const u16* Ap = A + (size_t)(m0 + sr) * K + sc;
    const u16* Bp = Bt + (size_t)(n0 + sr) * K + sc;
    u16* Asw = As + wave * 512;
    u16* Bsw = Bs + wave * 512;

    f32x4 acc[4][4];
    f32x4 z = {0.f, 0.f, 0.f, 0.f};
    for (int mi = 0; mi < 4; ++mi)
        for (int ni = 0; ni < 4; ++ni) acc[mi][ni] = z;

    for (int k0 = 0; k0 < K; k0 += 64) {
        gll16(Ap + k0, Asw);
        gll16(Ap + (size_t)64 * K + k0, Asw + 2048);
        gll16(Ap + k0 + 32, Asw + 4096);
        gll16(Ap + (size_t)64 * K + k0 + 32, Asw + 6144);
        gll16(Bp + k0, Bsw);
        gll16(Bp + (size_t)64 * K + k0, Bsw + 2048);
        gll16(Bp + k0 + 32, Bsw + 4096);
        gll16(Bp + (size_t)64 * K + k0 + 32, Bsw + 6144);
        __syncthreads();
        for (int kh = 0; kh < 2; ++kh) {
            const u16* Ab = As + kh * 4096;
            const u16* Bb = Bs + kh * 4096;
            s16x8 af[4], bfr[4];
            for (int mi = 0; mi < 4; ++mi)
                af[mi] = *(const s16x8*)&Ab[(wm + mi * 16 + lm) * 32 + lk];
            for (int ni = 0; ni < 4; ++ni)
                bfr[ni] = *(const s16x8*)&Bb[(wn + ni * 16 + lm) * 32 + lk];
            for (int mi = 0; mi < 4; ++mi)
                for (int ni = 0; ni < 4; ++ni)
                    acc[mi][ni] = __builtin_amdgcn_mfma_f32_16x16x32_bf16(
                        af[mi], bfr[ni], acc[mi][ni], 0, 0, 0);
        }
        __syncthreads();
    }

    int cn = lane & 15, cr = (lane >> 4) * 4;
    for (int ni = 0; ni < 4; ++ni) {
        int gn = n0 + wn + ni * 16 + cn;
        float bb = f ? b2f(((const u16*)bias)[gn]) : ((const float*)bias)[gn];
        for (int mi = 0; mi < 4; ++mi)
            for (int r = 0; r < 4; ++r) {
                int gm = m0 + wm + mi * 16 + cr + r;
                C[(size_t)gm * N + gn] = f2b(acc[mi][ni][r] + bb);
            }
    }
}

// ---- GEMM2: out = AO @ WtP^T + b. M=4096 N=1024 K=1024, 64x128, BK=64 ----
__global__ __launch_bounds__(256) void k_gemm2(
    const u16* __restrict__ Xraw, const u16* __restrict__ A,
    const u16* __restrict__ Bt, const void* __restrict__ bias,
    u16* __restrict__ Cb, float* __restrict__ Cf) {
    const int K = 1024, N = 1024;
    __shared__ u16 As[64 * 64];
    __shared__ u16 Bs[128 * 64];
    int f = sniff_bf16(Xraw);
    int t = threadIdx.x, wave = t >> 6, lane = t & 63;
    int m0 = blockIdx.y * 64, n0 = blockIdx.x * 128;
    int wm = (wave >> 1) * 32, wn = (wave & 1) * 64;
    int lm = lane & 15, lk = (lane >> 4) * 8;
    int sr = t >> 2, sc = (t & 3) * 8;
    const u16* Ap = A + (size_t)(m0 + sr) * K + sc;
    const u16* Bp = Bt + (size_t)(n0 + sr) * K + sc;
    u16* Asw = As + wave * 512;
    u16* Bsw = Bs + wave * 512;

    f32x4 acc[2][4];
    f32x4 z = {0.f, 0.f, 0.f, 0.f};
    for (int mi = 0; mi < 2; ++mi)
        for (int ni = 0; ni < 4; ++ni) acc[mi][ni] = z;

    for (int k0 = 0; k0 < K; k0 += 64) {
        gll16(Ap + k0, Asw);                           // A 64x32 half0
        gll16(Ap + k0 + 32, Asw + 2048);               // A half1
        gll16(Bp + k0, Bsw);                           // B rows 0-63 half0
        gll16(Bp + (size_t)64 * K + k0, Bsw + 2048);   // B rows 64-127 half0
        gll16(Bp + k0 + 32, Bsw + 4096);               // B rows 0-63 half1
        gll16(Bp + (size_t)64 * K + k0 + 32, Bsw + 6144);
        __syncthreads();
        for (int kh = 0; kh < 2; ++kh) {
            const u16* Ab = As + kh * 2048;
            const u16* Bb = Bs + kh * 4096;
            s16x8 af[2], bfr[4];
            for (int mi = 0; mi < 2; ++mi)
                af[mi] = *(const s16x8*)&Ab[(wm + mi * 16 + lm) * 32 + lk];
            for (int ni = 0; ni < 4; ++ni)
                bfr[ni] = *(const s16x8*)&Bb[(wn + ni * 16 + lm) * 32 + lk];
            for (int mi = 0; mi < 2; ++mi)
                for (int ni = 0; ni < 4; ++ni)
                    acc[mi][ni] = __builtin_amdgcn_mfma_f32_16x16x32_bf16(
                        af[mi], bfr[ni], acc[mi][ni], 0, 0, 0);
        }
        __syncthreads();
    }

    int store_f32 = (f == 0);
    int cn = lane & 15, cr = (lane >> 4) * 4;
    for (int ni = 0; ni < 4; ++ni) {
        int gn = n0 + wn + ni * 16 + cn;
        float bb = f ? b2f(((const u16*)bias)[gn]) : ((const float*)bias)[gn];
        for (int mi = 0; mi < 2; ++mi)
            for (int r = 0; r < 4; ++r) {
                int gm = m0 + wm + mi * 16 + cr + r;
                float v = acc[mi][ni][r] + bb;
                size_t o = (size_t)gm * N + gn;
                if (store_f32) Cf[o] = v;
                else           Cb[o] = f2b(v);
            }
    }
}

// ---- MFMA sparse attention (verified R3/R4) ----
#define VP 264
#define PP 264
__global__ __launch_bounds__(256) void k_attn3(const u16* __restrict__ QKV,
                                               u16* __restrict__ AO) {
    int bx = blockIdx.x, h = blockIdx.y, b = blockIdx.z;
    int qb = bx >> 1, sb = bx & 1;
    int t = threadIdx.x, lane = t & 63, wave = t >> 6;
    int lm = lane & 15, q4 = lane >> 4;
    int nstr = qb << 3;
    int nk = nstr + (sb << 6) + 64;     // <= 248
    int r0 = (qb << 7) + (sb << 6);

    __shared__ char smem[79872];
    u16* Vts = (u16*)smem;                       // 64 x 264 = 33792 B
    u16* Qs  = (u16*)(smem + 33792);             // 64 x 72
    u16* Ks  = (u16*)(smem + 33792 + 9216);      // 256 x 72
    u16* Ps  = (u16*)(smem + 33792);             // aliases Qs+Ks

    const u16* base = QKV + (size_t)b * SDIM * 3072;

    for (int c = t; c < 512; c += 256) {
        int r = c >> 3, d0 = (c & 7) << 3;
        *(uint4*)&Qs[r * 72 + d0] =
            *(const uint4*)(base + (size_t)(r0 + r) * 3072 + h * 64 + d0);
    }
    uint4 zz = {0u, 0u, 0u, 0u};
    for (int c = t; c < 2048; c += 256) {
        int i = c >> 3, d0 = (c & 7) << 3;
        uint4 kv = zz;
        if (i < nk) {
            int key = (i < nstr) ? (((i >> 3) << 7) + 120 + (i & 7))
                                 : ((qb << 7) + (i - nstr));
            kv = *(const uint4*)(base + (size_t)key * 3072 + 1024 + h * 64 + d0);
        }
        *(uint4*)&Ks[i * 72 + d0] = kv;
    }
    {
        int i0 = (t & 31) * 8, d0 = (t >> 5) * 8;
        u16 m8[8][8];
        for (int r = 0; r < 8; ++r) {
            int i = i0 + r;
            uint4 vv = zz;
            if (i < nk) {
                int key = (i < nstr) ? (((i >> 3) << 7) + 120 + (i & 7))
                                     : ((qb << 7) + (i - nstr));
                vv = *(const uint4*)(base + (size_t)key * 3072 + 2048 + h * 64 + d0);
            }
            *(uint4*)m8[r] = vv;
        }
        for (int j = 0; j < 8; ++j) {
            u16 o[8];
            for (int r = 0; r < 8; ++r) o[r] = m8[r][j];
            *(uint4*)&Vts[(d0 + j) * VP + i0] = *(uint4*)o;
        }
    }
    __syncthreads();

    f32x4 acc[16];
    f32x4 z4 = {0.f, 0.f, 0.f, 0.f};
    for (int ni = 0; ni < 16; ++ni) acc[ni] = z4;
    s16x8 af0 = *(const s16x8*)&Qs[(wave * 16 + lm) * 72 + q4 * 8];
    s16x8 af1 = *(const s16x8*)&Qs[(wave * 16 + lm) * 72 + 32 + q4 * 8];
    for (int ni = 0; ni < 16; ++ni) {
        s16x8 bf0 = *(const s16x8*)&Ks[(ni * 16 + lm) * 72 + q4 * 8];
        s16x8 bf1 = *(const s16x8*)&Ks[(ni * 16 + lm) * 72 + 32 + q4 * 8];
        acc[ni] = __builtin_amdgcn_mfma_f32_16x16x32_bf16(af0, bf0, acc[ni], 0, 0, 0);
        acc[ni] = __builtin_amdgcn_mfma_f32_16x16x32_bf16(af1, bf1, acc[ni], 0, 0, 0);
    }
    __syncthreads();

    float mx[4] = {-3e38f, -3e38f, -3e38f, -3e38f};
    for (int ni = 0; ni < 16; ++ni) {
        int i = ni * 16 + lm;
        for (int reg = 0; reg < 4; ++reg) {
            int rl = (sb << 6) + wave * 16 + q4 * 4 + reg;
            bool valid = (i < nstr) || ((i - nstr) <= rl);
            float v = valid ? acc[ni][reg] * 0.125f : -3e38f;
            acc[ni][reg] = v;
            mx[reg] = fmaxf(mx[reg], v);
        }
    }
    for (int reg = 0; reg < 4; ++reg)
        for (int off = 1; off < 16; off <<= 1)
            mx[reg] = fmaxf(mx[reg], __shfl_xor(mx[reg], off, 64));
    float sm[4] = {0.f, 0.f, 0.f, 0.f};
    for (int ni = 0; ni < 16; ++ni)
        for (int reg = 0; reg < 4; ++reg) {
            float e = __expf(acc[ni][reg] - mx[reg]);
            acc[ni][reg] = e;
            sm[reg] += e;
        }
    for (int reg = 0; reg < 4; ++reg)
        for (int off = 1; off < 16; off <<= 1)
            sm[reg] += __shfl_xor(sm[reg], off, 64);
    float inv[4];
    for (int reg = 0; reg < 4; ++reg) inv[reg] = 1.f / sm[reg];

    for (int ni = 0; ni < 16; ++ni) {
        int i = ni * 16 + lm;
        for (int reg = 0; reg < 4; ++reg)
            Ps[(wave * 16 + q4 * 4 + reg) * PP + i] = f2b(acc[ni][reg]);
    }
    __syncthreads();

    f32x4 acc2[4];
    for (int ni2 = 0; ni2 < 4; ++ni2) acc2[ni2] = z4;
    for (int k0 = 0; k0 < 256; k0 += 32) {
        s16x8 pf = *(const s16x8*)&Ps[(wave * 16 + lm) * PP + k0 + q4 * 8];
        for (int ni2 = 0; ni2 < 4; ++ni2) {
            s16x8 vf = *(const s16x8*)&Vts[(ni2 * 16 + lm) * VP + k0 + q4 * 8];
            acc2[ni2] = __builtin_amdgcn_mfma_f32_16x16x32_bf16(pf, vf, acc2[ni2], 0, 0, 0);
        }
    }
    int srow = r0 + wave * 16 + q4 * 4;
    for (int ni2 = 0; ni2 < 4; ++ni2)
        for (int reg = 0; reg < 4; ++reg) {
            size_t o = ((size_t)(b * SDIM + srow + reg)) * EDIM + h * 64 + ni2 * 16 + lm;
            AO[o] = f2b(acc2[ni2][reg] * inv[reg]);
        }
}

extern "C" void kernel_launch(void* const* d_in, const int* in_sizes, int n_in,
                              void* d_out, int out_size, void* d_ws, size_t ws_size,
                              hipStream_t stream) {
    const void* X  = d_in[0];
    const void* Wa = d_in[1];
    const void* ba = d_in[2];
    const void* Wp = d_in[3];
    const void* bp = d_in[4];

    char* w = (char*)d_ws;
    u16* Xb   = (u16*)(w);                  //  8388608
    u16* WtA  = (u16*)(w + 8388608);        //  6291456
    u16* WtP  = (u16*)(w + 14680064);       //  2097152
    u16* QKV  = (u16*)(w + 16777216);       // 25165824
    u16* AO   = (u16*)(w + 41943040);       //  8388608  (total 50331648)

    k_prep<<<dim3(48, 16, 3), 256, 0, stream>>>(X, Wa, Wp, Xb, WtA, WtP);
    k_gemm1<<<dim3(24, 32), 256, 0, stream>>>((const u16*)X, Xb, WtA, ba, QKV);
    k_attn3<<<dim3(32, 16, 2), 256, 0, stream>>>(QKV, AO);
    k_gemm2<<<dim3(8, 64), 256, 0, stream>>>((const u16*)X, AO, WtP, bp,
                                             (u16*)d_out, (float*)d_out);
}